// Round 1
// baseline (589.677 us; speedup 1.0000x reference)
//
#include <hip/hip_runtime.h>
#include <math.h>

#define D_HALF 512
#define D_MODEL 1024
#define MAX_SEQ 8192

// spine for MAX_SEQ_LEN=8192 (deterministic recurrence): [0,2,4,12,36,104,304,888,2592,7568]
__device__ __forceinline__ void pos_feats(int pos, float& f0, float& f1, float& f2) {
  constexpr int spine[10] = {0, 2, 4, 12, 36, 104, 304, 888, 2592, 7568};
  int lev = 1;       // spine[0]=0 <= pos always
  int left_base = 0;
#pragma unroll
  for (int i = 1; i < 10; ++i) {
    if (pos >= spine[i]) { lev++; left_base = spine[i]; }
  }
  int right = 0;     // level==10 -> 0
#pragma unroll
  for (int i = 9; i >= 1; --i) {
    if (pos < spine[i]) right = spine[i] - pos;  // ends at smallest spine > pos
  }
  f0 = (float)(pos - left_base);
  f1 = (float)right;
  f2 = (float)lev;
}

// Compute 4 lattice-encoding values for dims d=4t..4t+3 of position `pos`.
// stats: [m0,m1,m2,mb, C00,C01,C02,C0b, C11,C12,C1b, C22,C2b, Cbb]
__device__ __forceinline__ float4 lat_quad(int pos, int t,
    const float* __restrict__ W1, const float* __restrict__ b1,
    const float* __restrict__ gamma, const float* __restrict__ beta,
    const float* __restrict__ stats)
{
  float f0, f1, f2;
  pos_feats(pos, f0, f1, f2);
  const float m0 = stats[0], m1 = stats[1], m2 = stats[2], m3 = stats[3];
  const float C00 = stats[4],  C01 = stats[5],  C02 = stats[6],  C03 = stats[7];
  const float C11 = stats[8],  C12 = stats[9],  C13 = stats[10];
  const float C22 = stats[11], C23 = stats[12], C33 = stats[13];

  const float mu  = fmaf(m0, f0, fmaf(m1, f1, fmaf(m2, f2, m3)));
  const float var = C33
                  + f0 * (C00 * f0 + 2.0f * (C01 * f1 + C02 * f2 + C03))
                  + f1 * (C11 * f1 + 2.0f * (C12 * f2 + C13))
                  + f2 * (C22 * f2 + 2.0f * C23);
  const float rstd = rsqrtf(var + 1e-5f);

  const int d = 4 * t;
  const float4* wv = (const float4*)(W1 + 3 * d);  // 12 floats = 3 x float4, 16B aligned
  const float4 wa = wv[0], wb = wv[1], wc = wv[2];
  const float4 bb = ((const float4*)b1)[t];
  const float4 gg = ((const float4*)gamma)[t];
  const float4 be = ((const float4*)beta)[t];

  const float h0 = fmaf(wa.x, f0, fmaf(wa.y, f1, fmaf(wa.z, f2, bb.x)));
  const float h1 = fmaf(wa.w, f0, fmaf(wb.x, f1, fmaf(wb.y, f2, bb.y)));
  const float h2 = fmaf(wb.z, f0, fmaf(wb.w, f1, fmaf(wc.x, f2, bb.z)));
  const float h3 = fmaf(wc.y, f0, fmaf(wc.z, f1, fmaf(wc.w, f2, bb.w)));

  const float x0 = fmaf((h0 - mu) * rstd, gg.x, be.x);
  const float x1 = fmaf((h1 - mu) * rstd, gg.y, be.y);
  const float x2 = fmaf((h2 - mu) * rstd, gg.z, be.z);
  const float x3 = fmaf((h3 - mu) * rstd, gg.w, be.w);

  const float is2 = 0.70710678118654752440f;
  float4 r;
  r.x = 0.5f * x0 * (1.0f + erff(x0 * is2));
  r.y = 0.5f * x1 * (1.0f + erff(x1 * is2));
  r.z = 0.5f * x2 * (1.0f + erff(x2 * is2));
  r.w = 0.5f * x3 * (1.0f + erff(x3 * is2));
  return r;
}

// one block; reduce W1 [512,3] + b1 [512] -> 4 means + 10 covariances
__global__ __launch_bounds__(256) void lattice_stats(
    const float* __restrict__ W1, const float* __restrict__ b1,
    float* __restrict__ stats)
{
  const int t = threadIdx.x;
  float s[4] = {0.f, 0.f, 0.f, 0.f};
  float p[10] = {0.f, 0.f, 0.f, 0.f, 0.f, 0.f, 0.f, 0.f, 0.f, 0.f};
  for (int d = t; d < D_HALF; d += 256) {
    const float w0 = W1[3 * d], w1 = W1[3 * d + 1], w2 = W1[3 * d + 2], bb = b1[d];
    s[0] += w0; s[1] += w1; s[2] += w2; s[3] += bb;
    p[0] += w0 * w0; p[1] += w0 * w1; p[2] += w0 * w2; p[3] += w0 * bb;
    p[4] += w1 * w1; p[5] += w1 * w2; p[6] += w1 * bb;
    p[7] += w2 * w2; p[8] += w2 * bb; p[9] += bb * bb;
  }
  float vals[14] = {s[0], s[1], s[2], s[3], p[0], p[1], p[2], p[3], p[4],
                    p[5], p[6], p[7], p[8], p[9]};
#pragma unroll
  for (int i = 0; i < 14; ++i) {
    float v = vals[i];
#pragma unroll
    for (int off = 32; off > 0; off >>= 1) v += __shfl_down(v, off, 64);
    vals[i] = v;
  }
  __shared__ float sm[4][14];
  const int wave = t >> 6, lane = t & 63;
  if (lane == 0) {
#pragma unroll
    for (int i = 0; i < 14; ++i) sm[wave][i] = vals[i];
  }
  __syncthreads();
  if (t == 0) {
    float tot[14];
#pragma unroll
    for (int i = 0; i < 14; ++i) tot[i] = sm[0][i] + sm[1][i] + sm[2][i] + sm[3][i];
    const float inv = 1.0f / (float)D_HALF;
    const float m0 = tot[0] * inv, m1 = tot[1] * inv, m2 = tot[2] * inv, m3 = tot[3] * inv;
    stats[0] = m0; stats[1] = m1; stats[2] = m2; stats[3] = m3;
    stats[4]  = tot[4]  * inv - m0 * m0;  // C00
    stats[5]  = tot[5]  * inv - m0 * m1;  // C01
    stats[6]  = tot[6]  * inv - m0 * m2;  // C02
    stats[7]  = tot[7]  * inv - m0 * m3;  // C0b
    stats[8]  = tot[8]  * inv - m1 * m1;  // C11
    stats[9]  = tot[9]  * inv - m1 * m2;  // C12
    stats[10] = tot[10] * inv - m1 * m3;  // C1b
    stats[11] = tot[11] * inv - m2 * m2;  // C22
    stats[12] = tot[12] * inv - m2 * m3;  // C2b
    stats[13] = tot[13] * inv - m3 * m3;  // Cbb
  }
}

// build lat table for all 8192 positions: table[p*512 + d]
__global__ __launch_bounds__(256) void lattice_build_table(
    const float* __restrict__ W1, const float* __restrict__ b1,
    const float* __restrict__ gamma, const float* __restrict__ beta,
    const float* __restrict__ stats, float* __restrict__ table)
{
  const int p = blockIdx.x * 2 + threadIdx.y;  // 4096 blocks * 2 rows
  const int t = threadIdx.x;                   // 0..127, 4 dims each
  float4 r = lat_quad(p, t, W1, b1, gamma, beta, stats);
  ((float4*)(table + (size_t)p * D_HALF))[t] = r;
}

// main gather: out[row] = concat(pe[pos], table[pos])
__global__ __launch_bounds__(256) void lattice_gather(
    const int* __restrict__ positions, const float* __restrict__ pe,
    const float* __restrict__ table, float* __restrict__ out)
{
  const int row = blockIdx.x * 2 + threadIdx.y;
  const int t = threadIdx.x;  // 0..127
  const int pos = positions[row];
  const float4 pv = ((const float4*)(pe + (size_t)pos * D_HALF))[t];
  const float4 lv = ((const float4*)(table + (size_t)pos * D_HALF))[t];
  float* outRow = out + (size_t)row * D_MODEL;
  ((float4*)outRow)[t] = pv;
  ((float4*)(outRow + D_HALF))[t] = lv;
}

// fallback if ws too small: compute lat per output row directly
__global__ __launch_bounds__(256) void lattice_direct(
    const int* __restrict__ positions, const float* __restrict__ pe,
    const float* __restrict__ W1, const float* __restrict__ b1,
    const float* __restrict__ gamma, const float* __restrict__ beta,
    const float* __restrict__ stats, float* __restrict__ out)
{
  const int row = blockIdx.x * 2 + threadIdx.y;
  const int t = threadIdx.x;
  const int pos = positions[row];
  const float4 pv = ((const float4*)(pe + (size_t)pos * D_HALF))[t];
  float4 r = lat_quad(pos, t, W1, b1, gamma, beta, stats);
  float* outRow = out + (size_t)row * D_MODEL;
  ((float4*)outRow)[t] = pv;
  ((float4*)(outRow + D_HALF))[t] = r;
}

extern "C" void kernel_launch(void* const* d_in, const int* in_sizes, int n_in,
                              void* d_out, int out_size, void* d_ws, size_t ws_size,
                              hipStream_t stream) {
  const int*   positions = (const int*)d_in[0];
  const float* pe        = (const float*)d_in[1];
  const float* W1        = (const float*)d_in[2];
  const float* b1        = (const float*)d_in[3];
  const float* ln_gamma  = (const float*)d_in[4];
  const float* ln_beta   = (const float*)d_in[5];
  float* out = (float*)d_out;

  const int rows = in_sizes[0];  // B*S = 131072
  float* stats = (float*)d_ws;
  float* table = (float*)((char*)d_ws + 256);
  const size_t need = 256 + (size_t)MAX_SEQ * D_HALF * sizeof(float);

  hipLaunchKernelGGL(lattice_stats, dim3(1), dim3(256), 0, stream, W1, b1, stats);

  dim3 block(128, 2);
  if (ws_size >= need) {
    hipLaunchKernelGGL(lattice_build_table, dim3(MAX_SEQ / 2), block, 0, stream,
                       W1, b1, ln_gamma, ln_beta, stats, table);
    hipLaunchKernelGGL(lattice_gather, dim3(rows / 2), block, 0, stream,
                       positions, pe, table, out);
  } else {
    hipLaunchKernelGGL(lattice_direct, dim3(rows / 2), block, 0, stream,
                       positions, pe, W1, b1, ln_gamma, ln_beta, stats, out);
  }
}